// Round 4
// baseline (64122.040 us; speedup 1.0000x reference)
//
#include <hip/hip_runtime.h>
#include <cstdint>
#include <cstddef>

// Problem constants (fixed by the reference).
#define S_LEN 1024
#define HID   2048
#define HID3  6144
#define NBLK  256   // scan grid: one block per CU
#define NTHR  512   // 8 waves per block; wave w owns hidden element i = 8*blk + w

// ---------------------------------------------------------------------------
// Lightweight monotonic grid barrier (launched cooperatively, so all blocks
// are co-resident). Counter only ever increments; barrier g complete when
// count >= g * gridDim. Release on arrival, acquire (threadfence) on exit.
// ---------------------------------------------------------------------------
__device__ __forceinline__ void grid_sync(unsigned* cnt, unsigned target) {
  __syncthreads();
  if (threadIdx.x == 0) {
    __hip_atomic_fetch_add(cnt, 1u, __ATOMIC_RELEASE, __HIP_MEMORY_SCOPE_AGENT);
    while (__hip_atomic_load(cnt, __ATOMIC_RELAXED, __HIP_MEMORY_SCOPE_AGENT) < target)
      __builtin_amdgcn_s_sleep(1);
    __threadfence();   // acquire: invalidate caches so we see remote writes
  }
  __syncthreads();
}

// ---------------------------------------------------------------------------
// Persistent GRU scan for one layer.
//   phase 1: hmap = W_hm @ h_prev + b_hm           (2048 rows, 1 row/wave)
//   phase 2: gh   = W_hh @ hmap + b_hh; gates; h_new  (3 rows/wave + pointwise)
// Weights are streamed from L3 every step (fp32, ~64 MB/step).
// ---------------------------------------------------------------------------
__global__ void __launch_bounds__(NTHR, 1)
gru_scan(const float* __restrict__ gi,     // S x 3H
         const float* __restrict__ Whm,    // H x H
         const float* __restrict__ bhm,    // H
         const float* __restrict__ Whh,    // 3H x H
         const float* __restrict__ bhh,    // 3H
         const float* __restrict__ h0,     // H
         float* __restrict__ outs,         // S x H
         float* __restrict__ h_last,       // H
         float* hb0, float* hb1,           // ping-pong hidden buffers (H each)
         float* __restrict__ hmap,         // H
         unsigned* bar)
{
  const int w    = threadIdx.x >> 6;
  const int lane = threadIdx.x & 63;
  const int i    = (blockIdx.x << 3) + w;   // owned hidden element, 0..2047
  unsigned gen = 0;

  // init h_prev <- h0
  {
    int g = blockIdx.x * NTHR + threadIdx.x;
    if (g < HID) hb0[g] = h0[g];
  }
  gen++; grid_sync(bar, gen * NBLK);

#pragma unroll 1
  for (int t = 0; t < S_LEN; ++t) {
    const float* hprev = (t & 1) ? hb1 : hb0;
    float*       hnext = (t & 1) ? hb0 : hb1;

    // ---- phase 1: mapped hidden --------------------------------------
    const float4* wp = (const float4*)(Whm + (size_t)i * HID);
    const float4* hp = (const float4*)hprev;
    float acc = 0.f;
#pragma unroll
    for (int j = 0; j < 8; ++j) {
      float4 wv = wp[lane + j * 64];
      float4 hv = hp[lane + j * 64];
      acc += wv.x * hv.x + wv.y * hv.y + wv.z * hv.z + wv.w * hv.w;
    }
#pragma unroll
    for (int off = 32; off; off >>= 1) acc += __shfl_xor(acc, off);
    const float hmap_i = acc + bhm[i];
    if (lane == 0) hmap[i] = hmap_i;

    gen++; grid_sync(bar, gen * NBLK);

    // ---- phase 2: gate dots + pointwise update -----------------------
    float4 hv[8];
    const float4* hm = (const float4*)hmap;
#pragma unroll
    for (int j = 0; j < 8; ++j) hv[j] = hm[lane + j * 64];

    const float4* wr = (const float4*)(Whh + (size_t)i * HID);
    const float4* wz = (const float4*)(Whh + (size_t)(HID + i) * HID);
    const float4* wn = (const float4*)(Whh + (size_t)(2 * HID + i) * HID);
    float ar = 0.f, az = 0.f, an = 0.f;
#pragma unroll
    for (int j = 0; j < 8; ++j) {
      float4 rv = wr[lane + j * 64];
      float4 zv = wz[lane + j * 64];
      float4 nv = wn[lane + j * 64];
      ar += rv.x * hv[j].x + rv.y * hv[j].y + rv.z * hv[j].z + rv.w * hv[j].w;
      az += zv.x * hv[j].x + zv.y * hv[j].y + zv.z * hv[j].z + zv.w * hv[j].w;
      an += nv.x * hv[j].x + nv.y * hv[j].y + nv.z * hv[j].z + nv.w * hv[j].w;
    }
#pragma unroll
    for (int off = 32; off; off >>= 1) {
      ar += __shfl_xor(ar, off);
      az += __shfl_xor(az, off);
      an += __shfl_xor(an, off);
    }

    if (lane == 0) {
      const size_t gb = (size_t)t * HID3;
      const float gr = ar + bhh[i]       + gi[gb + i];
      const float gz = az + bhh[HID + i] + gi[gb + HID + i];
      const float r = 1.f / (1.f + expf(-gr));
      const float z = 1.f / (1.f + expf(-gz));
      const float n = tanhf(gi[gb + 2 * HID + i] + r * (an + bhh[2 * HID + i]));
      const float hnew = (1.f - z) * n + z * hmap_i;
      hnext[i] = hnew;
      outs[(size_t)t * HID + i] = hnew;
      if (t == S_LEN - 1) h_last[i] = hnew;
    }

    gen++; grid_sync(bar, gen * NBLK);
  }
}

// ---------------------------------------------------------------------------
// fp32 GEMM with bias: C[M][N] = A[M][K] @ W[N][K]^T + b[N]
// 128x128 tile, BK=16, 256 threads, 8x8 per-thread microtile.
// M=1024, N=6144, K=2048 here (all divisible; no bounds checks).
// ---------------------------------------------------------------------------
#define BM 128
#define BN 128
#define BK 16
#define TM 8
#define TN 8

__global__ void __launch_bounds__(256, 2)
gemm_bias(const float* __restrict__ A, const float* __restrict__ W,
          const float* __restrict__ b, float* __restrict__ C,
          int M, int N, int K)
{
  __shared__ float As[BK][BM + 4];
  __shared__ float Ws[BK][BN + 4];
  const int tid = threadIdx.x;
  const int nbn = N / BN;
  const int bx = blockIdx.x % nbn;   // n-tile
  const int by = blockIdx.x / nbn;   // m-tile
  const int tx = tid & 15;
  const int ty = tid >> 4;
  const int rowA0 = by * BM;
  const int colB0 = bx * BN;

  float acc[TM][TN] = {};

  const int lr  = tid >> 2;          // 0..63 (row within tile, +64 second pass)
  const int lc4 = (tid & 3) * 4;     // k offset within BK

  for (int k0 = 0; k0 < K; k0 += BK) {
#pragma unroll
    for (int p = 0; p < 2; ++p) {
      const int r = lr + p * 64;
      float4 av = *(const float4*)(A + (size_t)(rowA0 + r) * K + k0 + lc4);
      As[lc4 + 0][r] = av.x; As[lc4 + 1][r] = av.y;
      As[lc4 + 2][r] = av.z; As[lc4 + 3][r] = av.w;
      float4 wv = *(const float4*)(W + (size_t)(colB0 + r) * K + k0 + lc4);
      Ws[lc4 + 0][r] = wv.x; Ws[lc4 + 1][r] = wv.y;
      Ws[lc4 + 2][r] = wv.z; Ws[lc4 + 3][r] = wv.w;
    }
    __syncthreads();
#pragma unroll
    for (int kk = 0; kk < BK; ++kk) {
      float a[TM], wv[TN];
#pragma unroll
      for (int ii = 0; ii < TM; ++ii) a[ii] = As[kk][ty * TM + ii];
#pragma unroll
      for (int jj = 0; jj < TN; ++jj) wv[jj] = Ws[kk][tx * TN + jj];
#pragma unroll
      for (int ii = 0; ii < TM; ++ii)
#pragma unroll
        for (int jj = 0; jj < TN; ++jj) acc[ii][jj] += a[ii] * wv[jj];
    }
    __syncthreads();
  }

#pragma unroll
  for (int ii = 0; ii < TM; ++ii) {
    const int m = rowA0 + ty * TM + ii;
#pragma unroll
    for (int jj = 0; jj < TN; jj += 4) {
      const int n = colB0 + tx * TN + jj;
      float4 bv = *(const float4*)(b + n);
      float4 cv = { acc[ii][jj] + bv.x, acc[ii][jj + 1] + bv.y,
                    acc[ii][jj + 2] + bv.z, acc[ii][jj + 3] + bv.w };
      *(float4*)(C + (size_t)m * N + n) = cv;
    }
  }
}

// ---------------------------------------------------------------------------
extern "C" void kernel_launch(void* const* d_in, const int* in_sizes, int n_in,
                              void* d_out, int out_size, void* d_ws, size_t ws_size,
                              hipStream_t stream) {
  (void)in_sizes; (void)n_in; (void)out_size; (void)ws_size;

  const float* x    = (const float*)d_in[0];
  const float* hx   = (const float*)d_in[1];
  const float* Wih0 = (const float*)d_in[2];
  const float* bih0 = (const float*)d_in[3];
  const float* Whh0 = (const float*)d_in[4];
  const float* bhh0 = (const float*)d_in[5];
  const float* Whm0 = (const float*)d_in[6];
  const float* bhm0 = (const float*)d_in[7];
  const float* Wih1 = (const float*)d_in[8];
  const float* bih1 = (const float*)d_in[9];
  const float* Whh1 = (const float*)d_in[10];
  const float* bhh1 = (const float*)d_in[11];
  const float* Whm1 = (const float*)d_in[12];
  const float* bhm1 = (const float*)d_in[13];

  float* out = (float*)d_out;

  // workspace layout (floats)
  float* gi_buf = (float*)d_ws;                          // S * 3H
  float* outs0  = gi_buf + (size_t)S_LEN * HID3;         // S * H
  float* hb0    = outs0 + (size_t)S_LEN * HID;           // H
  float* hb1    = hb0 + HID;                             // H
  float* hmap   = hb1 + HID;                             // H
  unsigned* bar = (unsigned*)(hmap + HID);               // 1

  const dim3 gemm_grid((S_LEN / BM) * (HID3 / BN));
  const dim3 gemm_blk(256);

  // ---------------- layer 0 ----------------
  hipMemsetAsync(bar, 0, sizeof(unsigned), stream);
  gemm_bias<<<gemm_grid, gemm_blk, 0, stream>>>(x, Wih0, bih0, gi_buf,
                                                S_LEN, HID3, HID);
  {
    const float* h0 = hx;
    float* hl = out + (size_t)S_LEN * HID;
    void* args[] = {(void*)&gi_buf, (void*)&Whm0, (void*)&bhm0, (void*)&Whh0,
                    (void*)&bhh0, (void*)&h0, (void*)&outs0, (void*)&hl,
                    (void*)&hb0, (void*)&hb1, (void*)&hmap, (void*)&bar};
    hipLaunchCooperativeKernel((const void*)gru_scan, dim3(NBLK), dim3(NTHR),
                               args, 0, stream);
  }

  // ---------------- layer 1 ----------------
  hipMemsetAsync(bar, 0, sizeof(unsigned), stream);
  gemm_bias<<<gemm_grid, gemm_blk, 0, stream>>>(outs0, Wih1, bih1, gi_buf,
                                                S_LEN, HID3, HID);
  {
    const float* h0 = hx + HID;
    float* hl = out + (size_t)S_LEN * HID + HID;
    void* args[] = {(void*)&gi_buf, (void*)&Whm1, (void*)&bhm1, (void*)&Whh1,
                    (void*)&bhh1, (void*)&h0, (void*)&out, (void*)&hl,
                    (void*)&hb0, (void*)&hb1, (void*)&hmap, (void*)&bar};
    hipLaunchCooperativeKernel((const void*)gru_scan, dim3(NBLK), dim3(NTHR),
                               args, 0, stream);
  }
}

// Round 5
// 62131.195 us; speedup vs baseline: 1.0320x; 1.0320x over previous
//
#include <hip/hip_runtime.h>
#include <cstdint>
#include <cstddef>

// Problem constants (fixed by the reference).
#define S_LEN 1024
#define HID   2048
#define HID3  6144
#define NBLK  256   // scan grid: one block per CU
#define NTHR  512   // 8 waves per block; wave w owns hidden element i = 8*blk + w

// ---------------------------------------------------------------------------
// Monotonic grid barrier (cooperative launch => all blocks co-resident).
// Release on arrival, acquire (threadfence) on exit. Passed correctness in R4.
// ---------------------------------------------------------------------------
__device__ __forceinline__ void grid_sync(unsigned* cnt, unsigned target) {
  __syncthreads();
  if (threadIdx.x == 0) {
    __hip_atomic_fetch_add(cnt, 1u, __ATOMIC_RELEASE, __HIP_MEMORY_SCOPE_AGENT);
    while (__hip_atomic_load(cnt, __ATOMIC_RELAXED, __HIP_MEMORY_SCOPE_AGENT) < target)
      __builtin_amdgcn_s_sleep(1);
    __threadfence();   // acquire: invalidate caches so we see remote writes
  }
  __syncthreads();
}

// ---------------------------------------------------------------------------
// Register-resident GRU scan. Wave w of block b owns hidden element
// i = 8b + w and holds its 4 weight rows (W_hm[i], W_hh[i], W_hh[H+i],
// W_hh[2H+i]) in VGPRs for the whole scan: 128 floats/lane.
// Per step only the 8KB hidden vector (+3 gi scalars) crosses memory.
// Math ordering identical to the R4-passing kernel.
// ---------------------------------------------------------------------------
__global__ void __launch_bounds__(NTHR, 2)
gru_scan(const float* __restrict__ gi,     // S x 3H
         const float* __restrict__ Whm,    // H x H
         const float* __restrict__ bhm,    // H
         const float* __restrict__ Whh,    // 3H x H
         const float* __restrict__ bhh,    // 3H
         const float* __restrict__ h0,     // H
         float* __restrict__ outs,         // S x H
         float* __restrict__ h_last,       // H
         float* hb0, float* hb1,           // ping-pong hidden buffers (H each)
         float* __restrict__ hmap,         // H
         unsigned* bar)
{
  const int w    = threadIdx.x >> 6;
  const int lane = threadIdx.x & 63;
  const int i    = (blockIdx.x << 3) + w;   // owned hidden element, 0..2047

  // ---- one-time: weights into registers (32 float4 = 128 VGPRs) ----------
  float4 wm[8], wr_[8], wz_[8], wn_[8];
  {
    const float4* pm = (const float4*)(Whm + (size_t)i * HID);
    const float4* pr = (const float4*)(Whh + (size_t)i * HID);
    const float4* pz = (const float4*)(Whh + (size_t)(HID + i) * HID);
    const float4* pn = (const float4*)(Whh + (size_t)(2 * HID + i) * HID);
#pragma unroll
    for (int j = 0; j < 8; ++j) {
      wm[j]  = pm[lane + j * 64];
      wr_[j] = pr[lane + j * 64];
      wz_[j] = pz[lane + j * 64];
      wn_[j] = pn[lane + j * 64];
    }
  }
  const float bm_i = bhm[i];
  const float br_i = bhh[i];
  const float bz_i = bhh[HID + i];
  const float bn_i = bhh[2 * HID + i];

  // init h_prev <- h0
  {
    int g = blockIdx.x * NTHR + threadIdx.x;
    if (g < HID) hb0[g] = h0[g];
  }
  unsigned gen = 0;
  gen++; grid_sync(bar, gen * NBLK);

#pragma unroll 1
  for (int t = 0; t < S_LEN; ++t) {
    const float* hprev = (t & 1) ? hb1 : hb0;
    float*       hnext = (t & 1) ? hb0 : hb1;

    // early gi loads (lane 0 only; consumed after phase 2 — latency hidden)
    const size_t gb = (size_t)t * HID3;
    float g_r = 0.f, g_z = 0.f, g_n = 0.f;
    if (lane == 0) {
      g_r = gi[gb + i];
      g_z = gi[gb + HID + i];
      g_n = gi[gb + 2 * HID + i];
    }

    // ---- phase 1: hmap_i = W_hm[i] . h_prev + b_hm[i] -------------------
    float4 hv[8];
    {
      const float4* hp = (const float4*)hprev;
#pragma unroll
      for (int j = 0; j < 8; ++j) hv[j] = hp[lane + j * 64];
    }
    float am = 0.f;
#pragma unroll
    for (int j = 0; j < 8; ++j)
      am += wm[j].x * hv[j].x + wm[j].y * hv[j].y +
            wm[j].z * hv[j].z + wm[j].w * hv[j].w;
#pragma unroll
    for (int off = 32; off; off >>= 1) am += __shfl_xor(am, off);
    const float hmap_i = am + bm_i;
    if (lane == 0) hmap[i] = hmap_i;

    gen++; grid_sync(bar, gen * NBLK);

    // ---- phase 2: three gate dots on hmap + pointwise update ------------
    {
      const float4* hm = (const float4*)hmap;
#pragma unroll
      for (int j = 0; j < 8; ++j) hv[j] = hm[lane + j * 64];
    }
    float ar = 0.f, az = 0.f, an = 0.f;
#pragma unroll
    for (int j = 0; j < 8; ++j) {
      ar += wr_[j].x * hv[j].x + wr_[j].y * hv[j].y +
            wr_[j].z * hv[j].z + wr_[j].w * hv[j].w;
      az += wz_[j].x * hv[j].x + wz_[j].y * hv[j].y +
            wz_[j].z * hv[j].z + wz_[j].w * hv[j].w;
      an += wn_[j].x * hv[j].x + wn_[j].y * hv[j].y +
            wn_[j].z * hv[j].z + wn_[j].w * hv[j].w;
    }
#pragma unroll
    for (int off = 32; off; off >>= 1) {
      ar += __shfl_xor(ar, off);
      az += __shfl_xor(az, off);
      an += __shfl_xor(an, off);
    }

    if (lane == 0) {
      const float gr = ar + br_i + g_r;
      const float gz = az + bz_i + g_z;
      const float r = 1.f / (1.f + expf(-gr));
      const float z = 1.f / (1.f + expf(-gz));
      const float n = tanhf(g_n + r * (an + bn_i));
      const float hnew = (1.f - z) * n + z * hmap_i;
      hnext[i] = hnew;
      outs[(size_t)t * HID + i] = hnew;
      if (t == S_LEN - 1) h_last[i] = hnew;
    }

    gen++; grid_sync(bar, gen * NBLK);
  }
}

// ---------------------------------------------------------------------------
// fp32 GEMM with bias: C[M][N] = A[M][K] @ W[N][K]^T + b[N]
// 128x128 tile, BK=16, 256 threads, 8x8 per-thread microtile. (unchanged)
// ---------------------------------------------------------------------------
#define BM 128
#define BN 128
#define BK 16
#define TM 8
#define TN 8

__global__ void __launch_bounds__(256, 2)
gemm_bias(const float* __restrict__ A, const float* __restrict__ W,
          const float* __restrict__ b, float* __restrict__ C,
          int M, int N, int K)
{
  __shared__ float As[BK][BM + 4];
  __shared__ float Ws[BK][BN + 4];
  const int tid = threadIdx.x;
  const int nbn = N / BN;
  const int bx = blockIdx.x % nbn;   // n-tile
  const int by = blockIdx.x / nbn;   // m-tile
  const int tx = tid & 15;
  const int ty = tid >> 4;
  const int rowA0 = by * BM;
  const int colB0 = bx * BN;

  float acc[TM][TN] = {};

  const int lr  = tid >> 2;          // 0..63 (row within tile, +64 second pass)
  const int lc4 = (tid & 3) * 4;     // k offset within BK

  for (int k0 = 0; k0 < K; k0 += BK) {
#pragma unroll
    for (int p = 0; p < 2; ++p) {
      const int r = lr + p * 64;
      float4 av = *(const float4*)(A + (size_t)(rowA0 + r) * K + k0 + lc4);
      As[lc4 + 0][r] = av.x; As[lc4 + 1][r] = av.y;
      As[lc4 + 2][r] = av.z; As[lc4 + 3][r] = av.w;
      float4 wv = *(const float4*)(W + (size_t)(colB0 + r) * K + k0 + lc4);
      Ws[lc4 + 0][r] = wv.x; Ws[lc4 + 1][r] = wv.y;
      Ws[lc4 + 2][r] = wv.z; Ws[lc4 + 3][r] = wv.w;
    }
    __syncthreads();
#pragma unroll
    for (int kk = 0; kk < BK; ++kk) {
      float a[TM], wv[TN];
#pragma unroll
      for (int ii = 0; ii < TM; ++ii) a[ii] = As[kk][ty * TM + ii];
#pragma unroll
      for (int jj = 0; jj < TN; ++jj) wv[jj] = Ws[kk][tx * TN + jj];
#pragma unroll
      for (int ii = 0; ii < TM; ++ii)
#pragma unroll
        for (int jj = 0; jj < TN; ++jj) acc[ii][jj] += a[ii] * wv[jj];
    }
    __syncthreads();
  }

#pragma unroll
  for (int ii = 0; ii < TM; ++ii) {
    const int m = rowA0 + ty * TM + ii;
#pragma unroll
    for (int jj = 0; jj < TN; jj += 4) {
      const int n = colB0 + tx * TN + jj;
      float4 bv = *(const float4*)(b + n);
      float4 cv = { acc[ii][jj] + bv.x, acc[ii][jj + 1] + bv.y,
                    acc[ii][jj + 2] + bv.z, acc[ii][jj + 3] + bv.w };
      *(float4*)(C + (size_t)m * N + n) = cv;
    }
  }
}

// ---------------------------------------------------------------------------
extern "C" void kernel_launch(void* const* d_in, const int* in_sizes, int n_in,
                              void* d_out, int out_size, void* d_ws, size_t ws_size,
                              hipStream_t stream) {
  (void)in_sizes; (void)n_in; (void)out_size; (void)ws_size;

  const float* x    = (const float*)d_in[0];
  const float* hx   = (const float*)d_in[1];
  const float* Wih0 = (const float*)d_in[2];
  const float* bih0 = (const float*)d_in[3];
  const float* Whh0 = (const float*)d_in[4];
  const float* bhh0 = (const float*)d_in[5];
  const float* Whm0 = (const float*)d_in[6];
  const float* bhm0 = (const float*)d_in[7];
  const float* Wih1 = (const float*)d_in[8];
  const float* bih1 = (const float*)d_in[9];
  const float* Whh1 = (const float*)d_in[10];
  const float* bhh1 = (const float*)d_in[11];
  const float* Whm1 = (const float*)d_in[12];
  const float* bhm1 = (const float*)d_in[13];

  float* out = (float*)d_out;

  // workspace layout (floats)
  float* gi_buf = (float*)d_ws;                          // S * 3H
  float* outs0  = gi_buf + (size_t)S_LEN * HID3;         // S * H
  float* hb0    = outs0 + (size_t)S_LEN * HID;           // H
  float* hb1    = hb0 + HID;                             // H
  float* hmap   = hb1 + HID;                             // H
  unsigned* bar = (unsigned*)(hmap + HID);               // 1

  const dim3 gemm_grid((S_LEN / BM) * (HID3 / BN));
  const dim3 gemm_blk(256);

  // ---------------- layer 0 ----------------
  hipMemsetAsync(bar, 0, sizeof(unsigned), stream);
  gemm_bias<<<gemm_grid, gemm_blk, 0, stream>>>(x, Wih0, bih0, gi_buf,
                                                S_LEN, HID3, HID);
  {
    const float* h0 = hx;
    float* hl = out + (size_t)S_LEN * HID;
    void* args[] = {(void*)&gi_buf, (void*)&Whm0, (void*)&bhm0, (void*)&Whh0,
                    (void*)&bhh0, (void*)&h0, (void*)&outs0, (void*)&hl,
                    (void*)&hb0, (void*)&hb1, (void*)&hmap, (void*)&bar};
    hipLaunchCooperativeKernel((const void*)gru_scan, dim3(NBLK), dim3(NTHR),
                               args, 0, stream);
  }

  // ---------------- layer 1 ----------------
  hipMemsetAsync(bar, 0, sizeof(unsigned), stream);
  gemm_bias<<<gemm_grid, gemm_blk, 0, stream>>>(outs0, Wih1, bih1, gi_buf,
                                                S_LEN, HID3, HID);
  {
    const float* h0 = hx + HID;
    float* hl = out + (size_t)S_LEN * HID + HID;
    void* args[] = {(void*)&gi_buf, (void*)&Whm1, (void*)&bhm1, (void*)&Whh1,
                    (void*)&bhh1, (void*)&h0, (void*)&out, (void*)&hl,
                    (void*)&hb0, (void*)&hb1, (void*)&hmap, (void*)&bar};
    hipLaunchCooperativeKernel((const void*)gru_scan, dim3(NBLK), dim3(NTHR),
                               args, 0, stream);
  }
}

// Round 6
// 30466.858 us; speedup vs baseline: 2.1046x; 2.0393x over previous
//
#include <hip/hip_runtime.h>
#include <cstdint>
#include <cstddef>

// Problem constants (fixed by the reference).
#define S_LEN 1024
#define HID   2048
#define HID3  6144
#define NBLK  256   // scan grid: one block per CU
#define NTHR  512   // 8 waves per block; wave w owns hidden element i = 8*blk + w

// Force a value to stay materialized in VGPRs: opaque identity asm. The
// post-asm SSA value cannot be recreated by re-loading from memory, so the
// register allocator must keep it live (R5 lesson: plain local arrays get
// their loads sunk back into the loop; VGPR_Count stayed 108).
#define PIN4(v) asm volatile("" : "+v"((v).x), "+v"((v).y), "+v"((v).z), "+v"((v).w))

// ---------------------------------------------------------------------------
// Monotonic grid barrier (cooperative launch => all blocks co-resident).
// Passed correctness in R4/R5 — structure unchanged.
// ---------------------------------------------------------------------------
__device__ __forceinline__ void grid_sync(unsigned* cnt, unsigned target) {
  __syncthreads();
  if (threadIdx.x == 0) {
    __hip_atomic_fetch_add(cnt, 1u, __ATOMIC_RELEASE, __HIP_MEMORY_SCOPE_AGENT);
    while (__hip_atomic_load(cnt, __ATOMIC_RELAXED, __HIP_MEMORY_SCOPE_AGENT) < target)
      __builtin_amdgcn_s_sleep(1);
    __threadfence();   // acquire: invalidate caches so we see remote writes
  }
  __syncthreads();
}

// ---------------------------------------------------------------------------
// Fused register-resident GRU scan: ONE barrier per step.
//   gh   = A @ h_prev + c          (A = W_hh@W_hm, c = W_hh@b_hm + b_hh)
//   hmap = W_hm @ h_prev + b_hm    (needed exactly for the blend)
// Wave w of block b owns hidden element i = 8b + w and pins its 4 rows
// (A[i], A[H+i], A[2H+i], W_hm[i]) in VGPRs: 128 floats/lane.
// ---------------------------------------------------------------------------
__global__ void __launch_bounds__(NTHR, 2)
gru_scan_fused(const float* __restrict__ gi,    // S x 3H
               const float* __restrict__ A,     // 3H x H
               const float* __restrict__ Whm,   // H x H
               const float* __restrict__ c,     // 3H
               const float* __restrict__ bhm,   // H
               const float* __restrict__ h0,    // H
               float* __restrict__ outs,        // S x H
               float* __restrict__ h_last,      // H
               float* hb0, float* hb1,          // ping-pong hidden buffers
               unsigned* bar)
{
  const int w    = threadIdx.x >> 6;
  const int lane = threadIdx.x & 63;
  const int i    = (blockIdx.x << 3) + w;   // owned hidden element, 0..2047

  // ---- one-time: 4 weight rows into registers (32 float4 = 128 VGPRs) ----
  float4 wr4[8], wz4[8], wn4[8], wm4[8];
  {
    const float4* pr = (const float4*)(A   + (size_t)i * HID);
    const float4* pz = (const float4*)(A   + (size_t)(HID + i) * HID);
    const float4* pn = (const float4*)(A   + (size_t)(2 * HID + i) * HID);
    const float4* pm = (const float4*)(Whm + (size_t)i * HID);
#pragma unroll
    for (int j = 0; j < 8; ++j) {
      wr4[j] = pr[lane + j * 64];
      wz4[j] = pz[lane + j * 64];
      wn4[j] = pn[lane + j * 64];
      wm4[j] = pm[lane + j * 64];
    }
  }
#pragma unroll
  for (int j = 0; j < 8; ++j) { PIN4(wr4[j]); PIN4(wz4[j]); PIN4(wn4[j]); PIN4(wm4[j]); }

  const float cr_i = c[i];
  const float cz_i = c[HID + i];
  const float cn_i = c[2 * HID + i];
  const float bm_i = bhm[i];

  // init h_prev <- h0
  {
    int g = blockIdx.x * NTHR + threadIdx.x;
    if (g < HID) hb0[g] = h0[g];
  }
  unsigned gen = 0;
  gen++; grid_sync(bar, gen * NBLK);

#pragma unroll 1
  for (int t = 0; t < S_LEN; ++t) {
    const float* hprev = (t & 1) ? hb1 : hb0;
    float*       hnext = (t & 1) ? hb0 : hb1;

    // early gi loads (lane 0 only; consumed after dots — latency hidden)
    const size_t gb = (size_t)t * HID3;
    float g_r = 0.f, g_z = 0.f, g_n = 0.f;
    if (lane == 0) {
      g_r = gi[gb + i];
      g_z = gi[gb + HID + i];
      g_n = gi[gb + 2 * HID + i];
    }

    // ---- load h_prev slice, 4 dots, reduce ------------------------------
    float4 hv[8];
    {
      const float4* hp = (const float4*)hprev;
#pragma unroll
      for (int j = 0; j < 8; ++j) hv[j] = hp[lane + j * 64];
    }
    float ar = 0.f, az = 0.f, an = 0.f, am = 0.f;
#pragma unroll
    for (int j = 0; j < 8; ++j) {
      ar += wr4[j].x * hv[j].x + wr4[j].y * hv[j].y +
            wr4[j].z * hv[j].z + wr4[j].w * hv[j].w;
      az += wz4[j].x * hv[j].x + wz4[j].y * hv[j].y +
            wz4[j].z * hv[j].z + wz4[j].w * hv[j].w;
      an += wn4[j].x * hv[j].x + wn4[j].y * hv[j].y +
            wn4[j].z * hv[j].z + wn4[j].w * hv[j].w;
      am += wm4[j].x * hv[j].x + wm4[j].y * hv[j].y +
            wm4[j].z * hv[j].z + wm4[j].w * hv[j].w;
    }
#pragma unroll
    for (int off = 32; off; off >>= 1) {
      ar += __shfl_xor(ar, off);
      az += __shfl_xor(az, off);
      an += __shfl_xor(an, off);
      am += __shfl_xor(am, off);
    }

    if (lane == 0) {
      const float hmap_i = am + bm_i;
      const float gr = ar + cr_i + g_r;
      const float gz = az + cz_i + g_z;
      const float r = 1.f / (1.f + expf(-gr));
      const float z = 1.f / (1.f + expf(-gz));
      const float n = tanhf(g_n + r * (an + cn_i));
      const float hnew = (1.f - z) * n + z * hmap_i;
      hnext[i] = hnew;
      outs[(size_t)t * HID + i] = hnew;
      if (t == S_LEN - 1) h_last[i] = hnew;
    }

    gen++; grid_sync(bar, gen * NBLK);   // ONE barrier per step
  }
}

// ---------------------------------------------------------------------------
// 2048x2048 fp32 transpose: out[n][k] = in[k][n]. 32x32 LDS tile.
// ---------------------------------------------------------------------------
__global__ void transpose_sq(const float* __restrict__ in, float* __restrict__ out) {
  __shared__ float t[32][33];
  const int bx = blockIdx.x * 32, by = blockIdx.y * 32;
  const int x = threadIdx.x, y = threadIdx.y;   // block (32,8)
#pragma unroll
  for (int j = 0; j < 32; j += 8)
    t[y + j][x] = in[(size_t)(by + y + j) * HID + bx + x];
  __syncthreads();
#pragma unroll
  for (int j = 0; j < 32; j += 8)
    out[(size_t)(bx + y + j) * HID + by + x] = t[x][y + j];
}

// ---------------------------------------------------------------------------
// c[row] = W[row] . v + b[row]   (row-bias matvec, one wave per row)
// ---------------------------------------------------------------------------
__global__ void matvec_rowbias(const float* __restrict__ W, const float* __restrict__ v,
                               const float* __restrict__ b, float* __restrict__ c) {
  const int wv = threadIdx.x >> 6, lane = threadIdx.x & 63;
  const int row = blockIdx.x * 4 + wv;
  const float4* wp = (const float4*)(W + (size_t)row * HID);
  const float4* vp = (const float4*)v;
  float a = 0.f;
#pragma unroll
  for (int j = 0; j < 8; ++j) {
    float4 w4 = wp[lane + j * 64], v4 = vp[lane + j * 64];
    a += w4.x * v4.x + w4.y * v4.y + w4.z * v4.z + w4.w * v4.w;
  }
#pragma unroll
  for (int o = 32; o; o >>= 1) a += __shfl_xor(a, o);
  if (lane == 0) c[row] = a + b[row];
}

// ---------------------------------------------------------------------------
// fp32 GEMM with bias: C[M][N] = A[M][K] @ W[N][K]^T + b[N]   (unchanged)
// ---------------------------------------------------------------------------
#define BM 128
#define BN 128
#define BK 16
#define TM 8
#define TN 8

__global__ void __launch_bounds__(256, 2)
gemm_bias(const float* __restrict__ A, const float* __restrict__ W,
          const float* __restrict__ b, float* __restrict__ C,
          int M, int N, int K)
{
  __shared__ float As[BK][BM + 4];
  __shared__ float Ws[BK][BN + 4];
  const int tid = threadIdx.x;
  const int nbn = N / BN;
  const int bx = blockIdx.x % nbn;
  const int by = blockIdx.x / nbn;
  const int tx = tid & 15;
  const int ty = tid >> 4;
  const int rowA0 = by * BM;
  const int colB0 = bx * BN;

  float acc[TM][TN] = {};

  const int lr  = tid >> 2;
  const int lc4 = (tid & 3) * 4;

  for (int k0 = 0; k0 < K; k0 += BK) {
#pragma unroll
    for (int p = 0; p < 2; ++p) {
      const int r = lr + p * 64;
      float4 av = *(const float4*)(A + (size_t)(rowA0 + r) * K + k0 + lc4);
      As[lc4 + 0][r] = av.x; As[lc4 + 1][r] = av.y;
      As[lc4 + 2][r] = av.z; As[lc4 + 3][r] = av.w;
      float4 wv = *(const float4*)(W + (size_t)(colB0 + r) * K + k0 + lc4);
      Ws[lc4 + 0][r] = wv.x; Ws[lc4 + 1][r] = wv.y;
      Ws[lc4 + 2][r] = wv.z; Ws[lc4 + 3][r] = wv.w;
    }
    __syncthreads();
#pragma unroll
    for (int kk = 0; kk < BK; ++kk) {
      float a[TM], wv[TN];
#pragma unroll
      for (int ii = 0; ii < TM; ++ii) a[ii] = As[kk][ty * TM + ii];
#pragma unroll
      for (int jj = 0; jj < TN; ++jj) wv[jj] = Ws[kk][tx * TN + jj];
#pragma unroll
      for (int ii = 0; ii < TM; ++ii)
#pragma unroll
        for (int jj = 0; jj < TN; ++jj) acc[ii][jj] += a[ii] * wv[jj];
    }
    __syncthreads();
  }

#pragma unroll
  for (int ii = 0; ii < TM; ++ii) {
    const int m = rowA0 + ty * TM + ii;
#pragma unroll
    for (int jj = 0; jj < TN; jj += 4) {
      const int n = colB0 + tx * TN + jj;
      float4 bv = *(const float4*)(b + n);
      float4 cv = { acc[ii][jj] + bv.x, acc[ii][jj + 1] + bv.y,
                    acc[ii][jj + 2] + bv.z, acc[ii][jj + 3] + bv.w };
      *(float4*)(C + (size_t)m * N + n) = cv;
    }
  }
}

// ---------------------------------------------------------------------------
extern "C" void kernel_launch(void* const* d_in, const int* in_sizes, int n_in,
                              void* d_out, int out_size, void* d_ws, size_t ws_size,
                              hipStream_t stream) {
  (void)in_sizes; (void)n_in; (void)out_size; (void)ws_size;

  const float* x    = (const float*)d_in[0];
  const float* hx   = (const float*)d_in[1];
  const float* Wih[2] = {(const float*)d_in[2], (const float*)d_in[8]};
  const float* bih[2] = {(const float*)d_in[3], (const float*)d_in[9]};
  const float* Whh[2] = {(const float*)d_in[4], (const float*)d_in[10]};
  const float* bhh[2] = {(const float*)d_in[5], (const float*)d_in[11]};
  const float* Whm[2] = {(const float*)d_in[6], (const float*)d_in[12]};
  const float* bhm[2] = {(const float*)d_in[7], (const float*)d_in[13]};

  float* out = (float*)d_out;

  // workspace layout (floats). shared_buf holds At (16.8MB) then gi (25.2MB).
  float* A_buf  = (float*)d_ws;                            // 3H*H   (50.3MB)
  float* shared = A_buf + (size_t)HID3 * HID;              // max(At, gi)
  float* outs0  = shared + (size_t)S_LEN * HID3;           // S*H    (8.4MB)
  float* c_buf  = outs0 + (size_t)S_LEN * HID;             // 3H
  float* zb     = c_buf + HID3;                            // H zeros (gemm bias)
  float* hb0    = zb + HID;                                // H
  float* hb1    = hb0 + HID;                               // H
  unsigned* bar = (unsigned*)(hb1 + HID);                  // 1

  const dim3 gemmA_grid((HID3 / BM) * (HID / BN));   // 48*16 = 768
  const dim3 gemmG_grid((S_LEN / BM) * (HID3 / BN)); // 8*48  = 384
  const dim3 tr_grid(HID / 32, HID / 32);
  const dim3 tr_blk(32, 8);

  hipMemsetAsync(zb, 0, HID * sizeof(float), stream);

  for (int l = 0; l < 2; ++l) {
    hipMemsetAsync(bar, 0, sizeof(unsigned), stream);

    // A = W_hh @ W_hm  (via transpose + NT gemm), c = W_hh@b_hm + b_hh
    float* At = shared;
    transpose_sq<<<tr_grid, tr_blk, 0, stream>>>(Whm[l], At);
    gemm_bias<<<gemmA_grid, 256, 0, stream>>>(Whh[l], At, zb, A_buf,
                                              HID3, HID, HID);
    matvec_rowbias<<<HID3 / 4, 256, 0, stream>>>(Whh[l], bhm[l], bhh[l], c_buf);

    // gi = X @ W_ih^T + b_ih   (overwrites At region — no longer needed)
    const float* xin = (l == 0) ? x : outs0;
    float* gi = shared;
    gemm_bias<<<gemmG_grid, 256, 0, stream>>>(xin, Wih[l], bih[l], gi,
                                              S_LEN, HID3, HID);

    // fused scan
    const float* h0 = hx + (size_t)l * HID;
    float* outs = (l == 0) ? outs0 : out;
    float* hl = out + (size_t)S_LEN * HID + (size_t)l * HID;
    const float* Al = A_buf;
    const float* Wm = Whm[l];
    const float* cc = c_buf;
    const float* bm = bhm[l];
    void* args[] = {(void*)&gi, (void*)&Al, (void*)&Wm, (void*)&cc,
                    (void*)&bm, (void*)&h0, (void*)&outs, (void*)&hl,
                    (void*)&hb0, (void*)&hb1, (void*)&bar};
    hipLaunchCooperativeKernel((const void*)gru_scan_fused, dim3(NBLK), dim3(NTHR),
                               args, 0, stream);
  }
}

// Round 7
// 25908.945 us; speedup vs baseline: 2.4749x; 1.1759x over previous
//
#include <hip/hip_runtime.h>
#include <cstdint>
#include <cstddef>

// Problem constants (fixed by the reference).
#define S_LEN 1024
#define HID   2048
#define HID3  6144
#define NBLK  256   // scan grid: one block per CU
#define NTHR  512   // 8 waves per block; wave w owns hidden element i = 8*blk + w
#define FLAG_STRIDE 32   // uints per flag slot = 128B (one cache line)

// Force a value to stay materialized in VGPRs: opaque identity asm.
#define PIN4(v) asm volatile("" : "+v"((v).x), "+v"((v).y), "+v"((v).z), "+v"((v).w))

// ---------------------------------------------------------------------------
// Flag-array grid barrier (cooperative launch => all blocks co-resident).
// R6 counters showed the single-counter barrier costs ~13us/step: 256
// serialized device-scope atomic adds on one line. Here arrivals are
// parallel stores to per-block lines; block 0 polls and publishes one
// release word. Release/acquire semantics mirror the R4/R6-proven protocol
// (release store on arrival, relaxed spin + __threadfence on exit).
// Generations are monotonic within a dispatch; flags are zeroed per launch.
// ---------------------------------------------------------------------------
__device__ __forceinline__ void grid_sync(unsigned* flags, unsigned* release,
                                          unsigned gen) {
  __syncthreads();
  if (threadIdx.x == 0) {
    __hip_atomic_store(&flags[(size_t)blockIdx.x * FLAG_STRIDE], gen,
                       __ATOMIC_RELEASE, __HIP_MEMORY_SCOPE_AGENT);
  }
  if (blockIdx.x == 0) {
    if (threadIdx.x < 64) {
#pragma unroll
      for (int q = 0; q < NBLK / 64; ++q) {
        const int b = (int)threadIdx.x + q * 64;
        while (__hip_atomic_load(&flags[(size_t)b * FLAG_STRIDE],
                                 __ATOMIC_RELAXED, __HIP_MEMORY_SCOPE_AGENT) < gen)
          ;
      }
    }
    __syncthreads();              // all of block 0 knows: everyone arrived
    if (threadIdx.x == 0) {
      __threadfence();
      __hip_atomic_store(release, gen, __ATOMIC_RELEASE,
                         __HIP_MEMORY_SCOPE_AGENT);
    }
  }
  if (threadIdx.x == 0) {
    while (__hip_atomic_load(release, __ATOMIC_RELAXED,
                             __HIP_MEMORY_SCOPE_AGENT) < gen)
      __builtin_amdgcn_s_sleep(1);
    __threadfence();              // acquire: see remote h writes
  }
  __syncthreads();
}

// ---------------------------------------------------------------------------
// Fused register-resident GRU scan: ONE barrier per step.
//   gh   = A @ h_prev + c          (A = W_hh@W_hm, c = W_hh@b_hm + b_hh)
//   hmap = W_hm @ h_prev + b_hm
// Wave w of block b owns hidden element i = 8b + w; 4 weight rows pinned
// in VGPRs (128 floats/lane). launch_bounds(512,1): full 256-VGPR budget
// (R6: the (512,2) bound caused the 128-float pin to spill; VGPR was 96).
// ---------------------------------------------------------------------------
__global__ void __launch_bounds__(NTHR, 1)
gru_scan_fused(const float* __restrict__ gi,    // S x 3H
               const float* __restrict__ A,     // 3H x H
               const float* __restrict__ Whm,   // H x H
               const float* __restrict__ c,     // 3H
               const float* __restrict__ bhm,   // H
               const float* __restrict__ h0,    // H
               float* __restrict__ outs,        // S x H
               float* __restrict__ h_last,      // H
               float* hb0, float* hb1,          // ping-pong hidden buffers
               unsigned* flags, unsigned* release)
{
  const int w    = threadIdx.x >> 6;
  const int lane = threadIdx.x & 63;
  const int i    = (blockIdx.x << 3) + w;   // owned hidden element, 0..2047

  // ---- one-time: 4 weight rows into registers (32 float4 = 128 VGPRs) ----
  float4 wr4[8], wz4[8], wn4[8], wm4[8];
  {
    const float4* pr = (const float4*)(A   + (size_t)i * HID);
    const float4* pz = (const float4*)(A   + (size_t)(HID + i) * HID);
    const float4* pn = (const float4*)(A   + (size_t)(2 * HID + i) * HID);
    const float4* pm = (const float4*)(Whm + (size_t)i * HID);
#pragma unroll
    for (int j = 0; j < 8; ++j) {
      wr4[j] = pr[lane + j * 64];
      wz4[j] = pz[lane + j * 64];
      wn4[j] = pn[lane + j * 64];
      wm4[j] = pm[lane + j * 64];
    }
  }
#pragma unroll
  for (int j = 0; j < 8; ++j) { PIN4(wr4[j]); PIN4(wz4[j]); PIN4(wn4[j]); PIN4(wm4[j]); }

  const float cr_i = c[i];
  const float cz_i = c[HID + i];
  const float cn_i = c[2 * HID + i];
  const float bm_i = bhm[i];

  // init h_prev <- h0
  {
    int g = blockIdx.x * NTHR + threadIdx.x;
    if (g < HID) hb0[g] = h0[g];
  }
  unsigned gen = 1;
  grid_sync(flags, release, gen);

#pragma unroll 1
  for (int t = 0; t < S_LEN; ++t) {
    const float* hprev = (t & 1) ? hb1 : hb0;
    float*       hnext = (t & 1) ? hb0 : hb1;

    // early gi loads (lane 0 only; consumed after dots — latency hidden)
    const size_t gb = (size_t)t * HID3;
    float g_r = 0.f, g_z = 0.f, g_n = 0.f;
    if (lane == 0) {
      g_r = gi[gb + i];
      g_z = gi[gb + HID + i];
      g_n = gi[gb + 2 * HID + i];
    }

    // ---- load h_prev slice, 4 dots, reduce ------------------------------
    float4 hv[8];
    {
      const float4* hp = (const float4*)hprev;
#pragma unroll
      for (int j = 0; j < 8; ++j) hv[j] = hp[lane + j * 64];
    }
    float ar = 0.f, az = 0.f, an = 0.f, am = 0.f;
#pragma unroll
    for (int j = 0; j < 8; ++j) {
      ar += wr4[j].x * hv[j].x + wr4[j].y * hv[j].y +
            wr4[j].z * hv[j].z + wr4[j].w * hv[j].w;
      az += wz4[j].x * hv[j].x + wz4[j].y * hv[j].y +
            wz4[j].z * hv[j].z + wz4[j].w * hv[j].w;
      an += wn4[j].x * hv[j].x + wn4[j].y * hv[j].y +
            wn4[j].z * hv[j].z + wn4[j].w * hv[j].w;
      am += wm4[j].x * hv[j].x + wm4[j].y * hv[j].y +
            wm4[j].z * hv[j].z + wm4[j].w * hv[j].w;
    }
#pragma unroll
    for (int off = 32; off; off >>= 1) {
      ar += __shfl_xor(ar, off);
      az += __shfl_xor(az, off);
      an += __shfl_xor(an, off);
      am += __shfl_xor(am, off);
    }

    if (lane == 0) {
      const float hmap_i = am + bm_i;
      const float gr = ar + cr_i + g_r;
      const float gz = az + cz_i + g_z;
      const float r = 1.f / (1.f + expf(-gr));
      const float z = 1.f / (1.f + expf(-gz));
      const float n = tanhf(g_n + r * (an + cn_i));
      const float hnew = (1.f - z) * n + z * hmap_i;
      hnext[i] = hnew;
      outs[(size_t)t * HID + i] = hnew;
      if (t == S_LEN - 1) h_last[i] = hnew;
    }

    gen++;
    grid_sync(flags, release, gen);   // ONE barrier per step
  }
}

// ---------------------------------------------------------------------------
// 2048x2048 fp32 transpose: out[n][k] = in[k][n]. 32x32 LDS tile.
// ---------------------------------------------------------------------------
__global__ void transpose_sq(const float* __restrict__ in, float* __restrict__ out) {
  __shared__ float t[32][33];
  const int bx = blockIdx.x * 32, by = blockIdx.y * 32;
  const int x = threadIdx.x, y = threadIdx.y;   // block (32,8)
#pragma unroll
  for (int j = 0; j < 32; j += 8)
    t[y + j][x] = in[(size_t)(by + y + j) * HID + bx + x];
  __syncthreads();
#pragma unroll
  for (int j = 0; j < 32; j += 8)
    out[(size_t)(bx + y + j) * HID + by + x] = t[x][y + j];
}

// ---------------------------------------------------------------------------
// c[row] = W[row] . v + b[row]   (row-bias matvec, one wave per row)
// ---------------------------------------------------------------------------
__global__ void matvec_rowbias(const float* __restrict__ W, const float* __restrict__ v,
                               const float* __restrict__ b, float* __restrict__ c) {
  const int wv = threadIdx.x >> 6, lane = threadIdx.x & 63;
  const int row = blockIdx.x * 4 + wv;
  const float4* wp = (const float4*)(W + (size_t)row * HID);
  const float4* vp = (const float4*)v;
  float a = 0.f;
#pragma unroll
  for (int j = 0; j < 8; ++j) {
    float4 w4 = wp[lane + j * 64], v4 = vp[lane + j * 64];
    a += w4.x * v4.x + w4.y * v4.y + w4.z * v4.z + w4.w * v4.w;
  }
#pragma unroll
  for (int o = 32; o; o >>= 1) a += __shfl_xor(a, o);
  if (lane == 0) c[row] = a + b[row];
}

// ---------------------------------------------------------------------------
// fp32 GEMM with bias: C[M][N] = A[M][K] @ W[N][K]^T + b[N]   (unchanged)
// ---------------------------------------------------------------------------
#define BM 128
#define BN 128
#define BK 16
#define TM 8
#define TN 8

__global__ void __launch_bounds__(256, 2)
gemm_bias(const float* __restrict__ A, const float* __restrict__ W,
          const float* __restrict__ b, float* __restrict__ C,
          int M, int N, int K)
{
  __shared__ float As[BK][BM + 4];
  __shared__ float Ws[BK][BN + 4];
  const int tid = threadIdx.x;
  const int nbn = N / BN;
  const int bx = blockIdx.x % nbn;
  const int by = blockIdx.x / nbn;
  const int tx = tid & 15;
  const int ty = tid >> 4;
  const int rowA0 = by * BM;
  const int colB0 = bx * BN;

  float acc[TM][TN] = {};

  const int lr  = tid >> 2;
  const int lc4 = (tid & 3) * 4;

  for (int k0 = 0; k0 < K; k0 += BK) {
#pragma unroll
    for (int p = 0; p < 2; ++p) {
      const int r = lr + p * 64;
      float4 av = *(const float4*)(A + (size_t)(rowA0 + r) * K + k0 + lc4);
      As[lc4 + 0][r] = av.x; As[lc4 + 1][r] = av.y;
      As[lc4 + 2][r] = av.z; As[lc4 + 3][r] = av.w;
      float4 wv = *(const float4*)(W + (size_t)(colB0 + r) * K + k0 + lc4);
      Ws[lc4 + 0][r] = wv.x; Ws[lc4 + 1][r] = wv.y;
      Ws[lc4 + 2][r] = wv.z; Ws[lc4 + 3][r] = wv.w;
    }
    __syncthreads();
#pragma unroll
    for (int kk = 0; kk < BK; ++kk) {
      float a[TM], wv[TN];
#pragma unroll
      for (int ii = 0; ii < TM; ++ii) a[ii] = As[kk][ty * TM + ii];
#pragma unroll
      for (int jj = 0; jj < TN; ++jj) wv[jj] = Ws[kk][tx * TN + jj];
#pragma unroll
      for (int ii = 0; ii < TM; ++ii)
#pragma unroll
        for (int jj = 0; jj < TN; ++jj) acc[ii][jj] += a[ii] * wv[jj];
    }
    __syncthreads();
  }

#pragma unroll
  for (int ii = 0; ii < TM; ++ii) {
    const int m = rowA0 + ty * TM + ii;
#pragma unroll
    for (int jj = 0; jj < TN; jj += 4) {
      const int n = colB0 + tx * TN + jj;
      float4 bv = *(const float4*)(b + n);
      float4 cv = { acc[ii][jj] + bv.x, acc[ii][jj + 1] + bv.y,
                    acc[ii][jj + 2] + bv.z, acc[ii][jj + 3] + bv.w };
      *(float4*)(C + (size_t)m * N + n) = cv;
    }
  }
}

// ---------------------------------------------------------------------------
extern "C" void kernel_launch(void* const* d_in, const int* in_sizes, int n_in,
                              void* d_out, int out_size, void* d_ws, size_t ws_size,
                              hipStream_t stream) {
  (void)in_sizes; (void)n_in; (void)out_size; (void)ws_size;

  const float* x    = (const float*)d_in[0];
  const float* hx   = (const float*)d_in[1];
  const float* Wih[2] = {(const float*)d_in[2], (const float*)d_in[8]};
  const float* bih[2] = {(const float*)d_in[3], (const float*)d_in[9]};
  const float* Whh[2] = {(const float*)d_in[4], (const float*)d_in[10]};
  const float* bhh[2] = {(const float*)d_in[5], (const float*)d_in[11]};
  const float* Whm[2] = {(const float*)d_in[6], (const float*)d_in[12]};
  const float* bhm[2] = {(const float*)d_in[7], (const float*)d_in[13]};

  float* out = (float*)d_out;

  // workspace layout (floats). shared holds At (16.8MB) then gi (25.2MB).
  float* A_buf  = (float*)d_ws;                            // 3H*H   (50.3MB)
  float* shared = A_buf + (size_t)HID3 * HID;              // max(At, gi)
  float* outs0  = shared + (size_t)S_LEN * HID3;           // S*H    (8.4MB)
  float* c_buf  = outs0 + (size_t)S_LEN * HID;             // 3H
  float* zb     = c_buf + HID3;                            // H zeros (gemm bias)
  float* hb0    = zb + HID;                                // H
  float* hb1    = hb0 + HID;                               // H
  unsigned* flags = (unsigned*)(hb1 + HID);                // NBLK*32 + 32 uints
  unsigned* release = flags + (size_t)NBLK * FLAG_STRIDE;

  const dim3 gemmA_grid((HID3 / BM) * (HID / BN));   // 48*16 = 768
  const dim3 gemmG_grid((S_LEN / BM) * (HID3 / BN)); // 8*48  = 384
  const dim3 tr_grid(HID / 32, HID / 32);
  const dim3 tr_blk(32, 8);

  hipMemsetAsync(zb, 0, HID * sizeof(float), stream);

  for (int l = 0; l < 2; ++l) {
    // zero flags + release before each scan dispatch (gens restart at 1)
    hipMemsetAsync(flags, 0, ((size_t)NBLK * FLAG_STRIDE + FLAG_STRIDE) * sizeof(unsigned), stream);

    // A = W_hh @ W_hm  (via transpose + NT gemm), c = W_hh@b_hm + b_hh
    float* At = shared;
    transpose_sq<<<tr_grid, tr_blk, 0, stream>>>(Whm[l], At);
    gemm_bias<<<gemmA_grid, 256, 0, stream>>>(Whh[l], At, zb, A_buf,
                                              HID3, HID, HID);
    matvec_rowbias<<<HID3 / 4, 256, 0, stream>>>(Whh[l], bhm[l], bhh[l], c_buf);

    // gi = X @ W_ih^T + b_ih   (overwrites At region — no longer needed)
    const float* xin = (l == 0) ? x : outs0;
    float* gi = shared;
    gemm_bias<<<gemmG_grid, 256, 0, stream>>>(xin, Wih[l], bih[l], gi,
                                              S_LEN, HID3, HID);

    // fused scan
    const float* h0 = hx + (size_t)l * HID;
    float* outs = (l == 0) ? outs0 : out;
    float* hl = out + (size_t)S_LEN * HID + (size_t)l * HID;
    const float* Al = A_buf;
    const float* Wm = Whm[l];
    const float* cc = c_buf;
    const float* bm = bhm[l];
    void* args[] = {(void*)&gi, (void*)&Al, (void*)&Wm, (void*)&cc,
                    (void*)&bm, (void*)&h0, (void*)&outs, (void*)&hl,
                    (void*)&hb0, (void*)&hb1, (void*)&flags, (void*)&release};
    hipLaunchCooperativeKernel((const void*)gru_scan_fused, dim3(NBLK), dim3(NTHR),
                               args, 0, stream);
  }
}